// Round 11
// baseline (192.797 us; speedup 1.0000x reference)
//
#include <hip/hip_runtime.h>
#include <math.h>

// ---------------------------------------------------------------------------
// GCN 2-layer forward on MI355X.
// Round 22: build-phase diet (gathers measured saturated across R17-R21).
//  (1) csr.y = dinv[s]*ew; gathers use self-weight di and one final *di per
//      node (identical algebra) -> fill no longer reads dinv[d].
//  (2) per-node fill metadata packed: meta[d] = {rowptr_local, -, bases u64}
//      (one random 16B read) replacing rowptr[d]+bases[d] separate random
//      reads. Fill random CL touches/edge: ~5 -> 3.
//  (3) v_cvt_pk_bf16_f32 inline asm for fp32->bf16 pair packing (gemm1 A
//      conversion 24->4 VALU per frag; ag2s LDS pack). RNE = f2bf bitwise.
// Gather structure = R16/R21 (quarter-per-node, 8-deep, padded csr,
// prescaled src), hist = 8-replica (R19 proved replicas necessary).
// ---------------------------------------------------------------------------

typedef unsigned int uint32;
typedef unsigned long long u64;
typedef __attribute__((ext_vector_type(8))) short bf16x8;   // 8 bf16 (4 VGPRs)
typedef __attribute__((ext_vector_type(4))) float f32x4;
typedef __attribute__((ext_vector_type(2))) float f32x2;

__device__ __forceinline__ unsigned short f2bf(float f) {   // RNE fp32->bf16
    uint32 b = __float_as_uint(f);
    return (unsigned short)((b + 0x7FFFu + ((b >> 16) & 1u)) >> 16);
}

__device__ __forceinline__ uint32 cvtpk_bf16(float lo, float hi) {
    // packed RNE: dst.lo16 = bf16(lo), dst.hi16 = bf16(hi)
    uint32 r;
    asm("v_cvt_pk_bf16_f32 %0, %1, %2" : "=v"(r) : "v"(lo), "v"(hi));
    return r;
}

// ---------------------------------------------------------------------------
// MFMA GEMM body: H[n x 128] = A[n x 128] @ W (WT bf16 transposed).
// 256 threads = 4 waves; each wave 32 rows x 128 cols (2x8 16x16 tiles),
// K=128 in 4 steps. AFP32: A fp32 (converted inline via cvt_pk) vs bf16.
// OUTFP8: D written as fp8 e4m3 bytes vs bf16.
// ---------------------------------------------------------------------------
template <int AFP32, int OUTFP8>
__device__ __forceinline__ void gemm_body(const void* __restrict__ Ap,
                                          const unsigned short* __restrict__ WT,
                                          void* __restrict__ H,
                                          int n, int tb) {
    const int lane = threadIdx.x & 63;
    const int wv   = threadIdx.x >> 6;
    const int quad = lane >> 4;
    const int l16  = lane & 15;
    const int m0   = tb * 128 + wv * 32;
    f32x4 acc[2][8] = {};

    #pragma unroll
    for (int ks = 0; ks < 4; ++ks) {
        const int k0 = ks * 32 + quad * 8;
        bf16x8 a[2];
        #pragma unroll
        for (int rt = 0; rt < 2; ++rt) {
            int row = m0 + rt * 16 + l16;
            if (row >= n) row = n - 1;  // clamp; stores are guarded
            if (AFP32) {
                const float* Af = (const float*)Ap + (size_t)row * 128 + k0;
                float4 f0 = *(const float4*)(Af);
                float4 f1 = *(const float4*)(Af + 4);
                uint32 vv[4];
                vv[0] = cvtpk_bf16(f0.x, f0.y);
                vv[1] = cvtpk_bf16(f0.z, f0.w);
                vv[2] = cvtpk_bf16(f1.x, f1.y);
                vv[3] = cvtpk_bf16(f1.z, f1.w);
                a[rt] = *(const bf16x8*)vv;
            } else {
                const unsigned short* Ab = (const unsigned short*)Ap + (size_t)row * 128 + k0;
                a[rt] = *(const bf16x8*)Ab;
            }
        }
        #pragma unroll
        for (int ct = 0; ct < 8; ++ct) {
            bf16x8 b = *(const bf16x8*)(WT + (size_t)(ct * 16 + l16) * 128 + k0);
            acc[0][ct] = __builtin_amdgcn_mfma_f32_16x16x32_bf16(a[0], b, acc[0][ct], 0, 0, 0);
            acc[1][ct] = __builtin_amdgcn_mfma_f32_16x16x32_bf16(a[1], b, acc[1][ct], 0, 0, 0);
        }
    }

    // D layout: col = lane&15, row = quad*4 + reg  (m89-verified)
    #pragma unroll
    for (int rt = 0; rt < 2; ++rt) {
        #pragma unroll
        for (int r = 0; r < 4; ++r) {
            int row = m0 + rt * 16 + quad * 4 + r;
            if (row < n) {
                if (OUTFP8) {
                    unsigned char* o = (unsigned char*)H + (size_t)row * 128 + l16;
                    #pragma unroll
                    for (int cp = 0; cp < 4; ++cp) {
                        int pk = __builtin_amdgcn_cvt_pk_fp8_f32(
                            acc[rt][2 * cp][r], acc[rt][2 * cp + 1][r], 0, false);
                        o[(2 * cp) * 16]     = (unsigned char)(pk & 0xFF);
                        o[(2 * cp + 1) * 16] = (unsigned char)((pk >> 8) & 0xFF);
                    }
                } else {
                    unsigned short* o = (unsigned short*)H + (size_t)row * 128 + l16;
                    #pragma unroll
                    for (int ct = 0; ct < 8; ++ct)
                        o[ct * 16] = f2bf(acc[rt][ct][r]);
                }
            }
        }
    }
}

// ---------------------------------------------------------------------------
// Init: zero packed[8N u64] (as uint4) + done counter + 16 csr pad entries
// (src=0 pre-scaled, w=0); blocks [0,64) also transpose+convert W1/W2 to
// bf16 WT1/WT2.
// ---------------------------------------------------------------------------
__global__ __launch_bounds__(256) void k_init(u64* __restrict__ packed, int n4,
                                              int* __restrict__ done,
                                              float2* __restrict__ csr, int E,
                                              const float* __restrict__ W1,
                                              const float* __restrict__ W2,
                                              unsigned short* __restrict__ WT1,
                                              unsigned short* __restrict__ WT2) {
    int idx = blockIdx.x * 256 + threadIdx.x;
    if (idx < n4) ((uint4*)packed)[idx] = make_uint4(0u, 0u, 0u, 0u);
    if (idx == 0) *done = 0;
    if (idx < 16) csr[E + idx] = make_float2(0.0f, 0.0f);  // pad: row 0, w 0
    if (blockIdx.x < 64) {
        int j = blockIdx.x * 256 + threadIdx.x;  // 16384 total
        int k = j >> 7, nn = j & 127;
        WT1[nn * 128 + k] = f2bf(W1[k * 128 + nn]);
        WT2[nn * 128 + k] = f2bf(W2[k * 128 + nn]);
    }
}

// ---------------------------------------------------------------------------
// Fused gemm1 + hist: blocks [0,gGemm) compute h8 = fp8(x@W1) (MFMA pipe);
// blocks [gGemm, ...) do the 8-replica u64 histogram (atomic/TCC pipe).
// Replica r = (i>>8)&7, rank[i] = per-replica arrival order (atomic return).
// ---------------------------------------------------------------------------
__global__ __launch_bounds__(256) void k_gemm1_hist(const float* __restrict__ x,
                                                    const unsigned short* __restrict__ WT1,
                                                    unsigned char* __restrict__ h8,
                                                    const int* __restrict__ dst,
                                                    const float* __restrict__ ew,
                                                    u64* __restrict__ packed,
                                                    int* __restrict__ rank,
                                                    int E, int N, int gGemm) {
    const int b = blockIdx.x;
    if (b < gGemm) {
        gemm_body<1, 1>(x, WT1, h8, N, b);
        return;
    }
    int i = (b - gGemm) * 256 + threadIdx.x;
    if (i < E) {
        int d = dst[i];
        int r = (i >> 8) & 7;
        u64 add = (1ULL << 44) + (u64)(ew[i] * 4294967296.0f);
        u64 old = atomicAdd(&packed[(size_t)r * N + d], add);
        rank[i] = (int)(old >> 44);
    }
}

// ---------------------------------------------------------------------------
// Scan (one kernel): per-1024-chunk local exclusive scan of total counts into
// rowptr + packed fill-metadata meta[d] = {rowptr_local, 0, bases_lo,
// bases_hi}, fused decode (dinv), chunk totals release-stored into csums;
// last block (done counter) wave-scans the <=64 totals into exclusive
// chunk offsets in place.
// ---------------------------------------------------------------------------
__global__ __launch_bounds__(256) void k_scan(const u64* __restrict__ packed,
                                              float* __restrict__ dinv,
                                              uint4* __restrict__ meta,
                                              int* __restrict__ rowptr,
                                              int* __restrict__ csums,
                                              int* __restrict__ done, int nNodes) {
    __shared__ int s[256];
    __shared__ int lastFlag;
    const int t = threadIdx.x;
    const int base = blockIdx.x * 1024 + t * 4;
    const int n = nNodes + 1;  // scan domain: N counts + trailing 0
    int v[4];
    u64 bsv[4];
    #pragma unroll
    for (int u = 0; u < 4; ++u) {
        int idx = base + u;
        int c = 0;
        u64 bs = 0;
        if (idx < nNodes) {
            const u64 mask = (1ULL << 44) - 1;
            u64 ssum = 0;
            uint32 cum = 0;
            #pragma unroll
            for (int r = 0; r < 8; ++r) {
                u64 pv = packed[(size_t)r * nNodes + idx];
                bs |= (u64)cum << (8 * r);  // field 0 = 0
                cum += (uint32)(pv >> 44);
                ssum += (pv & mask);
            }
            c = (int)cum;
            float deg = 1.0f + (float)ssum * (1.0f / 4294967296.0f);
            dinv[idx] = rsqrtf(deg);
        }
        v[u] = c;
        bsv[u] = bs;
    }
    s[t] = v[0] + v[1] + v[2] + v[3];
    __syncthreads();
    #pragma unroll
    for (int off = 1; off < 256; off <<= 1) {
        int x = (t >= off) ? s[t - off] : 0;
        __syncthreads();
        s[t] += x;
        __syncthreads();
    }
    if (t == 255)
        __hip_atomic_store(&csums[blockIdx.x], s[255], __ATOMIC_RELEASE,
                           __HIP_MEMORY_SCOPE_AGENT);
    int e = (t == 0) ? 0 : s[t - 1];
    int rp[4];
    rp[0] = e;
    rp[1] = e + v[0];
    rp[2] = e + v[0] + v[1];
    rp[3] = e + v[0] + v[1] + v[2];
    #pragma unroll
    for (int u = 0; u < 4; ++u) {
        int idx = base + u;
        if (idx < n) rowptr[idx] = rp[u];
        if (idx < nNodes)
            meta[idx] = make_uint4((uint32)rp[u], 0u,
                                   (uint32)(bsv[u] & 0xFFFFFFFFu),
                                   (uint32)(bsv[u] >> 32));
    }

    // last-block: exclusive scan of the gridDim.x (<=64) chunk totals
    __syncthreads();  // all stores issued (incl. t255's release store)
    if (t == 0) {
        int prev = __hip_atomic_fetch_add(done, 1, __ATOMIC_ACQ_REL,
                                          __HIP_MEMORY_SCOPE_AGENT);
        lastFlag = (prev == (int)gridDim.x - 1);
    }
    __syncthreads();
    if (lastFlag && t < 64) {
        int g = (int)gridDim.x;
        int orig = (t < g) ? __hip_atomic_load(&csums[t], __ATOMIC_ACQUIRE,
                                               __HIP_MEMORY_SCOPE_AGENT)
                           : 0;
        int vv = orig;
        #pragma unroll
        for (int off = 1; off < 64; off <<= 1) {
            int y = __shfl_up(vv, off, 64);
            if (t >= off) vv += y;
        }
        if (t < g) csums[t] = vv - orig;  // exclusive chunk offset
    }
}

// Fill CSR (atomic-free):
//   pos = meta[d].rowlocal + csums[d>>10] + base_replica(meta[d], r) + rank.
// csr = (src*16 pre-scaled, dinv[s]*ew). dinv[d] is folded in at gather time.
__global__ __launch_bounds__(256) void k_fill(const int* __restrict__ src,
                                              const int* __restrict__ dst,
                                              const float* __restrict__ ew,
                                              const float* __restrict__ dinv,
                                              const uint4* __restrict__ meta,
                                              const int* __restrict__ csums,
                                              const int* __restrict__ rank,
                                              float2* __restrict__ csr, int e) {
    int i = blockIdx.x * 256 + threadIdx.x;
    if (i < e) {
        int s = src[i], d = dst[i];
        int r = (i >> 8) & 7;  // must match k_gemm1_hist's replica map
        uint4 m = meta[d];
        u64 bs = ((u64)m.w << 32) | (u64)m.z;
        float w = dinv[s] * ew[i];
        int pos = (int)m.x + csums[d >> 10]
                + (int)((bs >> (8 * r)) & 0xFF) + rank[i];
        csr[pos] = make_float2(__int_as_float(s << 4), w);
    }
}

// ---------------------------------------------------------------------------
// CSR gather helper: 8-wide fp32 FMA from fp8 (uint2) rows.
// ---------------------------------------------------------------------------
__device__ __forceinline__ void fma8_f8(float* acc, uint2 u, float w) {
    f32x2 f;
    f = __builtin_amdgcn_cvt_pk_f32_fp8((int)u.x, false);
    acc[0] += f[0] * w; acc[1] += f[1] * w;
    f = __builtin_amdgcn_cvt_pk_f32_fp8((int)u.x, true);
    acc[2] += f[0] * w; acc[3] += f[1] * w;
    f = __builtin_amdgcn_cvt_pk_f32_fp8((int)u.y, false);
    acc[4] += f[0] * w; acc[5] += f[1] * w;
    f = __builtin_amdgcn_cvt_pk_f32_fp8((int)u.y, true);
    acc[6] += f[0] * w; acc[7] += f[1] * w;
}

// ---------------------------------------------------------------------------
// Per-quarter CSR edge walk, software-pipelined: batch k+1's csr entries are
// loaded while batch k's 8 random row loads are in flight (csr is padded
// with 16 zero-weight entries past E; w-mask keeps out-of-row contributions
// at exactly 0). csr.x is pre-scaled src*16.
// ---------------------------------------------------------------------------
__device__ __forceinline__ void gather_q8p(float* acc, const uint2* __restrict__ T,
                                           const float2* __restrict__ csr,
                                           int start, int end, int l) {
    float2 c[8];
    #pragma unroll
    for (int j = 0; j < 8; ++j) c[j] = csr[start + j];   // padded-safe
    for (int k = start; k < end; k += 8) {
        uint2 u[8];
        float w[8];
        float2 cn[8];
        #pragma unroll
        for (int j = 0; j < 8; ++j) {
            w[j] = (k + j < end) ? c[j].y : 0.0f;
            u[j] = T[(size_t)(uint32)__float_as_int(c[j].x) + l];
        }
        #pragma unroll
        for (int j = 0; j < 8; ++j) cn[j] = csr[k + 8 + j];   // prefetch
        #pragma unroll
        for (int j = 0; j < 8; ++j) fma8_f8(acc, u[j], w[j]);
        #pragma unroll
        for (int j = 0; j < 8; ++j) c[j] = cn[j];
    }
}

// ---------------------------------------------------------------------------
// Layer-1 aggregation: g8 = fp8(relu(di*agg + b1)), agg = t[d] + sum w*t[s]
// with w = dinv_s*ew (self weight folded: di*(di*t[d]) == di^2 t[d]).
// Node-per-quarter: 16 nodes/block (4 waves x 4 quarters), 8-deep batches.
// ---------------------------------------------------------------------------
__global__ __launch_bounds__(256) void k_ag1(const unsigned char* __restrict__ h8,
                                             const float2* __restrict__ csr,
                                             const int* __restrict__ rowptr,
                                             const int* __restrict__ csums,
                                             const float* __restrict__ dinv,
                                             const float4* __restrict__ bias4,
                                             unsigned char* __restrict__ g8, int N) {
    const int lane = threadIdx.x & 63;
    const int q = lane >> 4, l = lane & 15;
    const int node = blockIdx.x * 16 + (threadIdx.x >> 6) * 4 + q;
    if (node >= N) return;   // lane-divergent ok: no barriers below
    const uint2* H2 = (const uint2*)h8;
    const int start = rowptr[node] + csums[node >> 10];
    const int end   = rowptr[node + 1] + csums[(node + 1) >> 10];
    const float di = dinv[node];

    float acc[8] = {};
    fma8_f8(acc, H2[(size_t)node * 16 + l], di);   // self-loop (di; x di later)
    gather_q8p(acc, H2, csr, start, end, l);

    float4 b0 = bias4[l * 2], b1v = bias4[l * 2 + 1];
    acc[0] = fmaf(acc[0], di, b0.x);  acc[1] = fmaf(acc[1], di, b0.y);
    acc[2] = fmaf(acc[2], di, b0.z);  acc[3] = fmaf(acc[3], di, b0.w);
    acc[4] = fmaf(acc[4], di, b1v.x); acc[5] = fmaf(acc[5], di, b1v.y);
    acc[6] = fmaf(acc[6], di, b1v.z); acc[7] = fmaf(acc[7], di, b1v.w);
    #pragma unroll
    for (int j = 0; j < 8; ++j) acc[j] = fmaxf(acc[j], 0.0f);
    uint2 o;
    int w0 = __builtin_amdgcn_cvt_pk_fp8_f32(acc[0], acc[1], 0, false);
    w0     = __builtin_amdgcn_cvt_pk_fp8_f32(acc[2], acc[3], w0, true);
    int w1 = __builtin_amdgcn_cvt_pk_fp8_f32(acc[4], acc[5], 0, false);
    w1     = __builtin_amdgcn_cvt_pk_fp8_f32(acc[6], acc[7], w1, true);
    o.x = (uint32)w0; o.y = (uint32)w1;
    ((uint2*)g8)[(size_t)node * 16 + l] = o;
}

// ---------------------------------------------------------------------------
// Layer-2 fused aggregate + GEMM + sigmoid (agg is linear: agg(g)@W2 ==
// agg(g@W2)). Block = 256 threads (4 waves) = 16 nodes, node-per-quarter.
// Phase 1: each quarter gathers its node over the fp8 g8 table, scales by
// di, writes bf16 rows (cvt_pk) into LDS sA[16][136] (pad 8 -> 2-way bank
// conflict = free). Phase 2: each wave computes the 16x32 col-slice of
// sA @ W2 at cols [wv*32,wv*32+32), adds b2, sigmoid, writes fp32 out.
// ---------------------------------------------------------------------------
__global__ __launch_bounds__(256) void k_ag2s(const unsigned char* __restrict__ g8,
                                              const float2* __restrict__ csr,
                                              const int* __restrict__ rowptr,
                                              const int* __restrict__ csums,
                                              const float* __restrict__ dinv,
                                              const float* __restrict__ b2,
                                              const unsigned short* __restrict__ WT2,
                                              float* __restrict__ out, int N) {
    __shared__ unsigned short sA[16][136];
    const int lane = threadIdx.x & 63;
    const int wv   = threadIdx.x >> 6;
    const int q    = lane >> 4;     // quarter (== MFMA quad later)
    const int l    = lane & 15;
    const int nb   = blockIdx.x * 16;
    const int node = nb + wv * 4 + q;
    const uint2* G2 = (const uint2*)g8;

    // ---- phase 1: each quarter gathers its node (no bias, no act) ----
    float acc[8] = {};
    uint4 o = make_uint4(0u, 0u, 0u, 0u);   // zero rows for node >= N
    if (node < N) {
        const int start = rowptr[node] + csums[node >> 10];
        const int end   = rowptr[node + 1] + csums[(node + 1) >> 10];
        const float di = dinv[node];
        fma8_f8(acc, G2[(size_t)node * 16 + l], di);   // self-loop
        gather_q8p(acc, G2, csr, start, end, l);
        #pragma unroll
        for (int j = 0; j < 8; ++j) acc[j] *= di;
        o.x = cvtpk_bf16(acc[0], acc[1]);
        o.y = cvtpk_bf16(acc[2], acc[3]);
        o.z = cvtpk_bf16(acc[4], acc[5]);
        o.w = cvtpk_bf16(acc[6], acc[7]);
    }
    *(uint4*)&sA[wv * 4 + q][l * 8] = o;

    __syncthreads();

    // ---- phase 2: out[nb..nb+16) = sigmoid(sA @ W2 + b2), cols [wv*32,+32) ----
    f32x4 a2[2] = {};
    #pragma unroll
    for (int ks = 0; ks < 4; ++ks) {
        const int k0 = ks * 32 + q * 8;
        bf16x8 a = *(const bf16x8*)&sA[l][k0];
        #pragma unroll
        for (int ct = 0; ct < 2; ++ct) {
            bf16x8 b = *(const bf16x8*)(WT2 + (size_t)(wv * 32 + ct * 16 + l) * 128 + k0);
            a2[ct] = __builtin_amdgcn_mfma_f32_16x16x32_bf16(a, b, a2[ct], 0, 0, 0);
        }
    }
    // D layout: col (within 16-tile) = lane&15, row = q*4 + reg
    #pragma unroll
    for (int ct = 0; ct < 2; ++ct) {
        const int col = wv * 32 + ct * 16 + l;
        const float bb = b2[col];
        #pragma unroll
        for (int r = 0; r < 4; ++r) {
            int row = nb + q * 4 + r;
            if (row < N) {
                float v = a2[ct][r] + bb;
                out[(size_t)row * 128 + col] = 1.0f / (1.0f + expf(-v));
            }
        }
    }
}

extern "C" void kernel_launch(void* const* d_in, const int* in_sizes, int n_in,
                              void* d_out, int out_size, void* d_ws, size_t ws_size,
                              hipStream_t stream) {
    const float* x  = (const float*)d_in[0];
    const int*   ei = (const int*)d_in[1];
    const float* ew = (const float*)d_in[2];
    const float* W1 = (const float*)d_in[3];
    const float* b1 = (const float*)d_in[4];
    const float* W2 = (const float*)d_in[5];
    const float* b2 = (const float*)d_in[6];

    const int N = in_sizes[0] / 128;
    const int E = in_sizes[2];
    const int* src = ei;
    const int* dst = ei + E;
    float* out = (float*)d_out;

    // Workspace layout (256B-aligned slabs):
    //   dinv [N] | rowptr [N+1] | csums [1024] | done | meta [N uint4]
    //   | WT1 | WT2 | rank [E] | csr [E+16 f2] | h8 [N*128 fp8]
    //   | g8 [N*128 fp8]
    //   (packed u64[8N] aliases g8: dead after k_scan, g8 written at k_ag1;
    //    8N u64 = 3.2 MB < 6.4 MB g8 slab)
    auto align = [](size_t v) { return (v + 255) & ~(size_t)255; };
    char* p = (char*)d_ws;
    float*  dinv   = (float*)p;   p += align((size_t)N * 4);
    int*    rowptr = (int*)p;     p += align((size_t)(N + 1) * 4);
    int*    csums  = (int*)p;     p += align((size_t)1024 * 4);
    int*    done   = (int*)p;     p += align((size_t)256);
    uint4*  meta   = (uint4*)p;   p += align((size_t)N * 16);
    unsigned short* WT1 = (unsigned short*)p; p += align((size_t)128 * 128 * 2);
    unsigned short* WT2 = (unsigned short*)p; p += align((size_t)128 * 128 * 2);
    int*    rank   = (int*)p;     p += align((size_t)E * 4);
    float2* csr    = (float2*)p;  p += align((size_t)(E + 16) * 8);
    unsigned char*  h8 = (unsigned char*)p;  p += align((size_t)N * 128);
    unsigned char*  g8 = (unsigned char*)p;
    u64* packed = (u64*)g8;  // alias (dead after scan; g8 written at ag1)

    const int nbE = (E + 255) / 256;
    const int gScan = (N + 1 + 1023) / 1024;   // 49 for N=50000 (<=64 required)
    const int gGemm = (N + 127) / 128;
    const int gAg1  = (N + 15) / 16;
    const int gAg2  = (N + 15) / 16;
    const int n4 = N * 4;                      // 8N u64 = 4N uint4
    const int gInit = ((n4 + 255) / 256) < 64 ? 64 : ((n4 + 255) / 256);

    // --- Build (+ layer-1 GEMM overlapped with hist) ---
    k_init<<<gInit, 256, 0, stream>>>(packed, n4, done, csr, E, W1, W2, WT1, WT2);
    k_gemm1_hist<<<gGemm + nbE, 256, 0, stream>>>(x, WT1, h8, dst, ew, packed,
                                                  rank, E, N, gGemm);
    k_scan<<<gScan, 256, 0, stream>>>(packed, dinv, meta, rowptr, csums, done, N);
    k_fill<<<nbE, 256, 0, stream>>>(src, dst, ew, dinv, meta, csums, rank,
                                    csr, E);

    // --- Layer 1: g8 = fp8(relu(di*agg(h8) + b1)) ---
    k_ag1<<<gAg1, 256, 0, stream>>>(h8, csr, rowptr, csums, dinv,
                                    (const float4*)b1, g8, N);

    // --- Layer 2 fused: out = sigmoid(agg(g8) @ W2 + b2) ---
    k_ag2s<<<gAg2, 256, 0, stream>>>(g8, csr, rowptr, csums, dinv, b2,
                                     WT2, out, N);
}